// Round 8
// baseline (151.271 us; speedup 1.0000x reference)
//
#include <hip/hip_runtime.h>

typedef __attribute__((ext_vector_type(8))) short short8;
typedef __attribute__((ext_vector_type(8))) __bf16 bf16x8;
typedef __attribute__((ext_vector_type(4))) float f32x4;

// sizes
#define B_ 4
#define C_ 64
#define H_ 128
#define W_ 128
#define P_ (H_*W_)      // 16384
#define E_ 16

// ws layout (bytes)
#define OFF_XT   0u
#define XT_BYTES (4u*130u*130u*64u*2u)          // 8,652,800
#define OFF_A    8652800u
#define OFF_R1   9832448u
#define OFF_PARA 14026752u

__device__ inline unsigned short f2bf(float f) {
    union { float f; unsigned u; } v; v.f = f;
    unsigned r = v.u + 0x7FFF + ((v.u >> 16) & 1);
    return (unsigned short)(r >> 16);
}

// ---------- transpose+pad x (NCHW f32) -> xt[b][y+1][x+1][c] bf16 ----------
// Also zeroes the halo (left/right cols; rows 0/129 by the y==0/127 blocks).
__global__ __launch_bounds__(128) void k_transpose(const float* __restrict__ x,
                                                   unsigned short* __restrict__ xt) {
    int b = blockIdx.x >> 7, y = blockIdx.x & 127;
    int t = threadIdx.x; // x coordinate
    const float* src = x + (size_t)b * C_ * P_ + y * W_ + t;
    unsigned short* dst = xt + ((size_t)(b * 130 + y + 1) * 130 + t + 1) * 64;
#pragma unroll
    for (int i = 0; i < 8; ++i) {
        short8 v;
#pragma unroll
        for (int j = 0; j < 8; ++j) v[j] = (short)f2bf(src[(size_t)(i * 8 + j) * P_]);
        ((short8*)dst)[i] = v;
    }
    short8 z = {0,0,0,0,0,0,0,0};
    if (t < 16) {
        int col = (t >> 3) * 129, i = t & 7;
        unsigned short* bp = xt + ((size_t)(b * 130 + y + 1) * 130 + col) * 64;
        ((short8*)bp)[i] = z;
    }
    if (y == 0 || y == 127) {
        int prow = (y == 0) ? 0 : 129;
        unsigned short* rp = xt + (size_t)(b * 130 + prow) * 130 * 64;
        for (int ci = t; ci < 1040; ci += 128) ((short8*)rp)[ci] = z;
    }
}

// ---------- build A[row=o*16+e][col=(kh*3+kw)*64+c] bf16 from W ----------
__global__ __launch_bounds__(256) void k_prepA(const float* __restrict__ Wsrc,
                                               unsigned short* __restrict__ A) {
    __shared__ float lw[9216];
    int o = blockIdx.x, t = threadIdx.x;
    const float* src = Wsrc + (size_t)o * 9216; // per o: [j=c*9+tap][e]
    for (int lin = t; lin < 9216; lin += 256) lw[lin] = src[lin];
    __syncthreads();
    unsigned short* dst = A + (size_t)o * 16 * 576;
    for (int lin = t; lin < 9216; lin += 256) {
        int e = lin / 576, col = lin - e * 576;
        int tap = col >> 6, c = col & 63;
        dst[e * 576 + col] = f2bf(lw[(c * 9 + tap) * 16 + e]);
    }
}

// ---------- predictor conv1x1 + relu -> r1[b][e][p] f32 ----------
__global__ __launch_bounds__(256) void k_pred1(const float* __restrict__ x,
                                               const float* __restrict__ pw,
                                               const float* __restrict__ pb,
                                               float* __restrict__ r1) {
    __shared__ float lpw[1024];
    __shared__ float lpb[16];
    int t = threadIdx.x;
    for (int lin = t; lin < 1024; lin += 256) lpw[lin] = pw[lin];
    if (t < 16) lpb[t] = pb[t];
    __syncthreads();
    int gp = blockIdx.x * 256 + t;
    int b = gp >> 14, p = gp & 16383;
    const float* xs = x + (size_t)b * C_ * P_ + p;
    float s[16];
#pragma unroll
    for (int e = 0; e < 16; ++e) s[e] = lpb[e];
    for (int c = 0; c < 64; ++c) {
        float xv = xs[(size_t)c * P_];
#pragma unroll
        for (int e = 0; e < 16; ++e) s[e] = fmaf(lpw[e * 64 + c], xv, s[e]);
    }
    float* d = r1 + (size_t)b * 16 * P_ + p;
#pragma unroll
    for (int e = 0; e < 16; ++e) d[(size_t)e * P_] = fmaxf(s[e], 0.f);
}

// ---------- predictor conv3x3 -> para[b][e][p] f32 ----------
__global__ __launch_bounds__(256) void k_pred2(const float* __restrict__ r1,
                                               const float* __restrict__ cw,
                                               const float* __restrict__ cb,
                                               float* __restrict__ para) {
    __shared__ float lcw[2304];
    __shared__ float lcb[16];
    int t = threadIdx.x;
    for (int lin = t; lin < 2304; lin += 256) lcw[lin] = cw[lin];
    if (t < 16) lcb[t] = cb[t];
    __syncthreads();
    int gp = blockIdx.x * 256 + t;
    int b = gp >> 14, p = gp & 16383;
    int y = p >> 7, xc = p & 127;
    const float* rs = r1 + (size_t)b * 16 * P_;
    float s[16];
#pragma unroll
    for (int e = 0; e < 16; ++e) s[e] = lcb[e];
    for (int dy = 0; dy < 3; ++dy) {
        int yy = y + dy - 1;
        if (yy < 0 || yy > 127) continue;
        for (int dx = 0; dx < 3; ++dx) {
            int xv = xc + dx - 1;
            if (xv < 0 || xv > 127) continue;
            int q = yy * 128 + xv;
            int tap = dy * 3 + dx;
#pragma unroll
            for (int ep = 0; ep < 16; ++ep) {
                float v = rs[(size_t)ep * P_ + q];
#pragma unroll
                for (int e = 0; e < 16; ++e)
                    s[e] = fmaf(lcw[(e * 16 + ep) * 9 + tap], v, s[e]);
            }
        }
    }
    float* d = para + (size_t)b * 16 * P_ + p;
#pragma unroll
    for (int e = 0; e < 16; ++e) d[(size_t)e * P_] = s[e];
}

// ---------- main fused kernel ----------
// 512 threads (8 waves), 4 image rows x 16 o's. LDS: A triple-buffer (24,576 B
// at offset 0, ds-offset-immediate friendly) + xt 6 rows (99,840 B) = 124,416.
// Per chunk: A-slice (8 o x 16 e x 576) staged per-K-step via global_load_lds
// (1 issue/wave/step, 2 steps ahead, triple-buffered, vmcnt(1) counted waits --
// never drained to 0 in-loop). 18 static bodies, barrier-pinned, setprio'd.
#define GLD(gp, lp) __builtin_amdgcn_global_load_lds( \
    (const __attribute__((address_space(1))) void*)(gp), \
    (__attribute__((address_space(3))) void*)(lp), 16, 0, 0)

__global__ __launch_bounds__(512, 2) void k_main(const unsigned short* __restrict__ xt,
                                                 const unsigned short* __restrict__ A,
                                                 const float* __restrict__ para,
                                                 float* __restrict__ out) {
    __shared__ __align__(16) char smem[24576 + 99840]; // A bufs | xt rows
    char* ldsA = smem;
    char* ldsX = smem + 24576;

    int r = blockIdx.x;
    int xcd = r & 7;
    int ord = r >> 3;
    int osl = ord & 3;          // o-slice: 16 o's
    int bygl = ord >> 2;        // [0,16)
    int byg = bygl * 8 + xcd;   // [0,128)
    int b = byg >> 5, yg = byg & 31;
    int y0 = yg * 4;

    int tid = threadIdx.x;
    int wave = tid >> 6, lane = tid & 63, lhi = lane >> 4, llo = lane & 15;
    int wrow = wave & 3, ohalf = wave >> 2;

    // stage 6 padded xt rows (y0..y0+5), swizzle byte ^= ((xx&7)<<4)
    const unsigned short* xrow = xt + (size_t)(b * 130 + y0) * 130 * 64;
    for (int ci = tid; ci < 6240; ci += 512) {
        int row = ci / 1040, rem = ci - row * 1040;
        int xx = rem >> 3, cc = rem & 7;
        short8 v = *(const short8*)(xrow + ((size_t)row * 130 + xx) * 64 + cc * 8);
        int lb = row * 16640 + xx * 128 + ((cc * 16) ^ ((xx & 7) << 4));
        *(short8*)(ldsX + lb) = v;
    }
    __syncthreads(); // full drain -> vmcnt clean before the A pipeline

    int y = y0 + wrow;
    const float* pp = para + (size_t)b * 16 * P_ + y * 128;
    float* po = out + (size_t)b * 64 * P_ + y * 128;

    // LDS B-read vaddrs: qv[parity][kw]; full addr = qv + kh*16640 + pg*2048
    int qv[2][3];
#pragma unroll
    for (int kw = 0; kw < 3; ++kw) {
        int rowi = llo + kw;
        int base0 = wrow * 16640 + rowi * 128 + ((lhi * 16) ^ ((rowi & 7) << 4));
        qv[0][kw] = base0;
        qv[1][kw] = base0 ^ 64;
    }
    const char* ldsc = (const char*)ldsX;

    // A staging roles: wave stages tile rows r8 = wave*16 + (lane>>2), slot = lane&3.
    // Tile row r8 = (o8*16 + e), o8 = ohalf*4+f. Slot swizzle: lds slot holds
    // global j-chunk (slot ^ ((r8>>1)&3)); (r8>>1)&3 == (lane>>3)&3 on stage side,
    // (llo>>1)&3 on read side.
    int e_st = lane >> 2;
    int slotsrc = (lane & 3) ^ ((lane >> 3) & 3);
    char* Aw = ldsA + wave * 1024; // + buf*8192; lane*16 applied by HW
    // af read: vaddr afv, + imm (buf*8192 + f*1024)
    int afv = (ohalf * 4) * 1024 + llo * 64 + ((lhi ^ ((llo >> 1) & 3)) << 4);

#define BODY(KS) do { \
    constexpr int KH_ = (KS) / 6, KW_ = ((KS) % 6) >> 1, PAR_ = (KS) & 1; \
    asm volatile("s_waitcnt vmcnt(%0)" :: "i"(((KS) == 17) ? 0 : 1) : "memory"); \
    __builtin_amdgcn_s_barrier(); \
    if ((KS) < 16) GLD(Ag + ((KS) + 2) * 64, Aw + ((((KS) + 2) % 3) * 8192)); \
    bf16x8 af[4]; \
    _Pragma("unroll") \
    for (int f_ = 0; f_ < 4; ++f_) \
        af[f_] = *(const bf16x8*)(ldsA + ((KS) % 3) * 8192 + afv + f_ * 1024); \
    const char* bp_ = ldsc + qv[PAR_][KW_] + KH_ * 16640; \
    bf16x8 bf[8]; \
    _Pragma("unroll") \
    for (int pg_ = 0; pg_ < 8; ++pg_) bf[pg_] = *(const bf16x8*)(bp_ + pg_ * 2048); \
    __builtin_amdgcn_s_setprio(1); \
    _Pragma("unroll") \
    for (int f_ = 0; f_ < 4; ++f_) \
    _Pragma("unroll") \
    for (int pg_ = 0; pg_ < 8; ++pg_) \
        acc[f_][pg_] = __builtin_amdgcn_mfma_f32_16x16x32_bf16(af[f_], bf[pg_], acc[f_][pg_], 0, 0, 0); \
    __builtin_amdgcn_s_setprio(0); \
} while (0)

#pragma unroll 1
    for (int c = 0; c < 2; ++c) {
        // per-lane global A source for this chunk's 8-o tile
        int o_glob = osl * 16 + (wave >> 2) * 8 + c * 4 + (wave & 3);
        const char* Ag = (const char*)A + (size_t)(o_glob * 16 + e_st) * 1152 + slotsrc * 16;

        f32x4 acc[4][8];
#pragma unroll
        for (int f = 0; f < 4; ++f)
#pragma unroll
            for (int pg = 0; pg < 8; ++pg) acc[f][pg] = (f32x4){0.f, 0.f, 0.f, 0.f};

        // prologue: stage ks=0,1
        GLD(Ag + 0, Aw + 0);
        GLD(Ag + 64, Aw + 8192);

        BODY(0);  BODY(1);  BODY(2);  BODY(3);  BODY(4);  BODY(5);
        BODY(6);  BODY(7);  BODY(8);  BODY(9);  BODY(10); BODY(11);
        BODY(12); BODY(13); BODY(14); BODY(15); BODY(16); BODY(17);

        // epilogue: multiply rows (e) by para[e,p], reduce over e
        int obase = osl * 16 + ohalf * 8 + c * 4;
        float pvv[8][4];
#pragma unroll
        for (int pg = 0; pg < 8; ++pg)
#pragma unroll
            for (int rr = 0; rr < 4; ++rr)
                pvv[pg][rr] = pp[(size_t)(lhi * 4 + rr) * P_ + pg * 16 + llo];

#pragma unroll
        for (int f = 0; f < 4; ++f) {
            int o = obase + f;
#pragma unroll
            for (int pg = 0; pg < 8; ++pg) {
                float s = acc[f][pg][0] * pvv[pg][0] + acc[f][pg][1] * pvv[pg][1] +
                          acc[f][pg][2] * pvv[pg][2] + acc[f][pg][3] * pvv[pg][3];
                s += __shfl_xor(s, 16);
                s += __shfl_xor(s, 32);
                if (lhi == 0)
                    __builtin_nontemporal_store(s, &po[(size_t)o * P_ + pg * 16 + llo]);
            }
        }
        // drain epilogue vmem so next chunk's vmcnt counting stays exact
        asm volatile("s_waitcnt vmcnt(0)" ::: "memory");
    }
#undef BODY
}

extern "C" void kernel_launch(void* const* d_in, const int* in_sizes, int n_in,
                              void* d_out, int out_size, void* d_ws, size_t ws_size,
                              hipStream_t stream) {
    const float* x  = (const float*)d_in[0];
    const float* W  = (const float*)d_in[1];
    const float* pw = (const float*)d_in[2];
    const float* pb = (const float*)d_in[3];
    const float* cw = (const float*)d_in[4];
    const float* cb = (const float*)d_in[5];
    float* out = (float*)d_out;
    char* ws = (char*)d_ws;
    unsigned short* xt = (unsigned short*)(ws + OFF_XT);
    unsigned short* Am = (unsigned short*)(ws + OFF_A);
    float* r1   = (float*)(ws + OFF_R1);
    float* para = (float*)(ws + OFF_PARA);

    hipLaunchKernelGGL(k_transpose, dim3(B_ * H_), dim3(128), 0, stream, x, xt);
    hipLaunchKernelGGL(k_prepA, dim3(64), dim3(256), 0, stream, W, Am);
    hipLaunchKernelGGL(k_pred1, dim3(B_ * P_ / 256), dim3(256), 0, stream, x, pw, pb, r1);
    hipLaunchKernelGGL(k_pred2, dim3(B_ * P_ / 256), dim3(256), 0, stream, r1, cw, cb, para);
    hipLaunchKernelGGL(k_main, dim3(512), dim3(512), 0, stream, xt, Am, para, out);
}